// Round 12
// baseline (3265.524 us; speedup 1.0000x reference)
//
#include <hip/hip_runtime.h>

#define NSEQ 4096
#define DM 768
#define WLD 2304

// ======= f32 tiled GEMM: C = A·B^T (TB=false) or C = A·B (TB=true) =======
template<bool TB, bool BIAS>
__global__ __launch_bounds__(256)
void gemm32(const float* __restrict__ A, long lda, int zdA, long sOA, long sIA,
            const float* __restrict__ B, long ldb, int zdB, long sOB, long sIB,
            float* __restrict__ C, long ldc, int zdC, long sOC, long sIC,
            int K, const float* __restrict__ bias)
{
    __shared__ float As[64][17];
    __shared__ float Bs[16][72];
    const int tid = threadIdx.x;
    const int z = blockIdx.z;
    const float* Ab = A + (long)(z/zdA)*sOA + (long)(z%zdA)*sIA;
    const float* Bb = B + (long)(z/zdB)*sOB + (long)(z%zdB)*sIB;
    const long coff = (long)(z/zdC)*sOC + (long)(z%zdC)*sIC;
    const int bm0 = blockIdx.y*64, bn0 = blockIdx.x*64;
    const int tx = tid & 15, ty = tid >> 4;
    float acc[4][4] = {};
    for (int k0 = 0; k0 < K; k0 += 16) {
        {
            const int r = tid >> 2, c4 = (tid & 3)*4;
            float4 v = *(const float4*)(Ab + (long)(bm0+r)*lda + k0 + c4);
            As[r][c4] = v.x; As[r][c4+1] = v.y; As[r][c4+2] = v.z; As[r][c4+3] = v.w;
        }
        if (TB) {
            const int kk = tid >> 4, n4 = (tid & 15)*4;
            float4 v = *(const float4*)(Bb + (long)(k0+kk)*ldb + bn0 + n4);
            *(float4*)&Bs[kk][n4] = v;
        } else {
            const int n = tid >> 2, k4 = (tid & 3)*4;
            float4 v = *(const float4*)(Bb + (long)(bn0+n)*ldb + k0 + k4);
            Bs[k4][n] = v.x; Bs[k4+1][n] = v.y; Bs[k4+2][n] = v.z; Bs[k4+3][n] = v.w;
        }
        __syncthreads();
        #pragma unroll
        for (int k = 0; k < 16; ++k) {
            float a[4], b[4];
            #pragma unroll
            for (int i = 0; i < 4; ++i) a[i] = As[ty*4+i][k];
            #pragma unroll
            for (int j = 0; j < 4; ++j) b[j] = Bs[k][tx*4+j];
            #pragma unroll
            for (int i = 0; i < 4; ++i)
                #pragma unroll
                for (int j = 0; j < 4; ++j)
                    acc[i][j] += a[i]*b[j];
        }
        __syncthreads();
    }
    #pragma unroll
    for (int i = 0; i < 4; ++i) {
        const int row = bm0 + ty*4 + i;
        #pragma unroll
        for (int j = 0; j < 4; ++j) {
            const int col = bn0 + tx*4 + j;
            float v = acc[i][j];
            if (BIAS) v += bias[col];
            C[coff + (long)row*ldc + col] = v;
        }
    }
}

// ======= landmarks (rows 65*m, linspace) q_l/k_l in f64 (+ f32 copies) =======
__global__ __launch_bounds__(256) void landmark_kernel(
    const float* __restrict__ x, const float* __restrict__ w_qkv,
    const float* __restrict__ b_qkv,
    double* __restrict__ QL, double* __restrict__ KL,
    float* __restrict__ qlf, float* __restrict__ klf)
{
    __shared__ float xs[64*65];
    __shared__ float wq[64*65];
    __shared__ float wk[64*65];
    const int z = blockIdx.x, b = z/12, h = z%12;
    const int t = threadIdx.x, m = t & 63, dg = t >> 6;
    double qa[16] = {}, ka[16] = {};
    for (int c = 0; c < 12; ++c) {
        const int D0 = c*64;
        for (int i = t; i < 4096; i += 256) {
            int r = i >> 6, dd = i & 63;
            xs[r*65+dd] = x[((long)b*NSEQ + r*65)*DM + D0 + dd];   // idx = 65*r (linspace)
            wq[r*65+dd] = w_qkv[(long)(D0+r)*WLD + h*64 + dd];
            wk[r*65+dd] = w_qkv[(long)(D0+r)*WLD + 768 + h*64 + dd];
        }
        __syncthreads();
        for (int dd = 0; dd < 64; ++dd) {
            double xv = (double)xs[m*65+dd];
            #pragma unroll
            for (int j = 0; j < 16; ++j) {
                qa[j] += xv * (double)wq[dd*65 + dg*16 + j];
                ka[j] += xv * (double)wk[dd*65 + dg*16 + j];
            }
        }
        __syncthreads();
    }
    #pragma unroll
    for (int j = 0; j < 16; ++j) {
        const int d = dg*16 + j;
        double q = qa[j] + (double)b_qkv[h*64 + d];
        double k = ka[j] + (double)b_qkv[768 + h*64 + d];
        const long o = ((long)z*64 + m)*64 + d;
        QL[o] = q;  KL[o] = k;
        qlf[o] = (float)q;  klf[o] = (float)k;
    }
}

// ======= row softmax len 64: L1[b][n][h*64+m] -> P1[z][n][m] (f32) =======
__global__ void softmax64_kernel(const float* __restrict__ L, float* __restrict__ P,
                                 float scale)
{
    const int w = threadIdx.x >> 6, lane = threadIdx.x & 63;
    const long R = (long)blockIdx.x*4 + w;   // R = (b*4096+n)*12 + h
    const int h = (int)(R % 12);
    const long bn = R / 12;
    const int b = (int)(bn >> 12);
    const int n = (int)(bn & 4095);
    const int z = b*12 + h;
    float xv = L[R*64 + lane] * scale;
    float mx = xv;
    #pragma unroll
    for (int off = 32; off; off >>= 1) mx = fmaxf(mx, __shfl_xor(mx, off));
    float e = __expf(xv - mx);
    float s = e;
    #pragma unroll
    for (int off = 32; off; off >>= 1) s += __shfl_xor(s, off);
    P[((long)z*NSEQ + n)*64 + lane] = e / s;
}

// ======= row softmax len 4096, in-place f32 =======
__global__ __launch_bounds__(256) void softmax4096_kernel(float* __restrict__ L, float scale)
{
    const long base = (long)blockIdx.x * 4096;
    const int t = threadIdx.x;
    __shared__ float red[4], red2[4];
    float v[16];
    float mx = -1e30f;
    #pragma unroll
    for (int i = 0; i < 16; ++i) { v[i] = L[base + t + i*256]*scale; mx = fmaxf(mx, v[i]); }
    #pragma unroll
    for (int off = 32; off; off >>= 1) mx = fmaxf(mx, __shfl_xor(mx, off));
    if ((t & 63) == 0) red[t >> 6] = mx;
    __syncthreads();
    mx = fmaxf(fmaxf(red[0], red[1]), fmaxf(red[2], red[3]));
    float s = 0.f;
    #pragma unroll
    for (int i = 0; i < 16; ++i) { v[i] = __expf(v[i] - mx); s += v[i]; }
    #pragma unroll
    for (int off = 32; off; off >>= 1) s += __shfl_xor(s, off);
    if ((t & 63) == 0) red2[t >> 6] = s;
    __syncthreads();
    const float inv = 1.0f / (red2[0] + red2[1] + red2[2] + red2[3]);
    #pragma unroll
    for (int i = 0; i < 16; ++i) L[base + t + i*256] = v[i]*inv;
}

// ======= k3v = P3 @ v with f64 accumulation -> k3v[z][m][d] (f64) =======
__global__ __launch_bounds__(256) void k3v64_kernel(
    const float* __restrict__ P3, const float* __restrict__ v,
    double* __restrict__ k3v)
{
    __shared__ float ps[64][65];
    __shared__ float vs[64][65];
    const int z = blockIdx.x, b = z/12, h = z%12;
    const int t = threadIdx.x;
    const int i0 = (t >> 4)*4, j0 = (t & 15)*4;
    double acc[4][4] = {};
    for (int n0 = 0; n0 < NSEQ; n0 += 64) {
        for (int i = t; i < 4096; i += 256) {
            int r = i >> 6, c = i & 63;
            ps[r][c] = P3[((long)(b*768 + h*64 + r))*NSEQ + n0 + c];
            vs[r][c] = v[((long)b*NSEQ + n0 + r)*DM + h*64 + c];
        }
        __syncthreads();
        for (int k = 0; k < 64; ++k) {
            double a[4], bb[4];
            #pragma unroll
            for (int r = 0; r < 4; ++r) a[r] = (double)ps[i0+r][k];
            #pragma unroll
            for (int c = 0; c < 4; ++c) bb[c] = (double)vs[k][j0+c];
            #pragma unroll
            for (int r = 0; r < 4; ++r)
                #pragma unroll
                for (int c = 0; c < 4; ++c) acc[r][c] += a[r]*bb[c];
        }
        __syncthreads();
    }
    #pragma unroll
    for (int r = 0; r < 4; ++r)
        #pragma unroll
        for (int c = 0; c < 4; ++c)
            k3v[((long)z*64 + (i0+r))*64 + (j0+c)] = acc[r][c];
}

// ======= f64 truncated pinv via A^T A Jacobi eigen + tmp2 = pinv @ k3v =======
// cutoff: keep sigma > rtol*sigma_max, rtol = 10*64*eps_f32 = 640*2^-23 = 7.62939453125e-5
__global__ __launch_bounds__(256) void pinv_tmp2_kernel(
    const double* __restrict__ QL, const double* __restrict__ KL,
    const double* __restrict__ k3v, float* __restrict__ t2)
{
    __shared__ double A_[64][64];
    __shared__ double S_[64][66];
    __shared__ double Q_[64][66];
    __shared__ double lam[64];
    __shared__ double cr[32], sr[32];
    __shared__ int    pa[32], qa[32];
    __shared__ double lmax_s;
    __shared__ double k3s[64][65];
    const int z = blockIdx.x;
    const int t = threadIdx.x;
    // stage landmarks (QL->S_, KL->Q_) and k3v
    for (int i = t; i < 4096; i += 256) {
        int m = i >> 6, d = i & 63;
        S_[m][d] = QL[((long)z*64+m)*64+d];
        Q_[m][d] = KL[((long)z*64+m)*64+d];
        k3s[m][d] = k3v[((long)z*64+m)*64+d];
    }
    __syncthreads();
    const int i0 = (t >> 4)*4, j0 = (t & 15)*4;
    // logits -> A_
    {
        double sc[4][4] = {};
        for (int k = 0; k < 64; ++k) {
            double a[4], b[4];
            #pragma unroll
            for (int r = 0; r < 4; ++r) a[r] = S_[i0+r][k];
            #pragma unroll
            for (int c = 0; c < 4; ++c) b[c] = Q_[j0+c][k];
            #pragma unroll
            for (int r = 0; r < 4; ++r)
                #pragma unroll
                for (int c = 0; c < 4; ++c) sc[r][c] += a[r]*b[c];
        }
        #pragma unroll
        for (int r = 0; r < 4; ++r)
            #pragma unroll
            for (int c = 0; c < 4; ++c)
                A_[i0+r][j0+c] = sc[r][c]*0.125;
    }
    __syncthreads();
    // row softmax + 1e-6 ridge
    {
        const int w = t >> 6, lane = t & 63;
        for (int r = w; r < 64; r += 4) {
            double xv = A_[r][lane];
            double mx = xv;
            #pragma unroll
            for (int off = 32; off; off >>= 1) mx = fmax(mx, __shfl_xor(mx, off));
            double e = exp(xv - mx);
            double su = e;
            #pragma unroll
            for (int off = 32; off; off >>= 1) su += __shfl_xor(su, off);
            double val = e/su;
            if (lane == r) val += 1e-6;
            A_[r][lane] = val;
        }
    }
    __syncthreads();
    // S_ = A^T A ; Q_ = I
    {
        double sc[4][4] = {};
        for (int k = 0; k < 64; ++k) {
            double a[4], b[4];
            #pragma unroll
            for (int r = 0; r < 4; ++r) a[r] = A_[k][i0+r];
            #pragma unroll
            for (int c = 0; c < 4; ++c) b[c] = A_[k][j0+c];
            #pragma unroll
            for (int r = 0; r < 4; ++r)
                #pragma unroll
                for (int c = 0; c < 4; ++c) sc[r][c] += a[r]*b[c];
        }
        #pragma unroll
        for (int r = 0; r < 4; ++r)
            #pragma unroll
            for (int c = 0; c < 4; ++c)
                S_[i0+r][j0+c] = sc[r][c];
    }
    for (int i = t; i < 4096; i += 256) {
        int r = i >> 6, c = i & 63;
        Q_[r][c] = (r == c) ? 1.0 : 0.0;
    }
    __syncthreads();
    // parallel cyclic Jacobi, 12 sweeps x 63 round-robin steps
    for (int sweep = 0; sweep < 12; ++sweep) {
        for (int step = 0; step < 63; ++step) {
            if (t < 32) {
                int p, q;
                if (t == 0) { p = 63; q = step; }
                else { p = (step + t) % 63; q = (step - t + 63) % 63; }
                double app = S_[p][p], aqq = S_[q][q], apq = S_[p][q];
                double c = 1.0, s = 0.0;
                if (fabs(apq) > 1e-300) {
                    double tau = (aqq - app) / (2.0*apq);
                    double tt = ((tau >= 0.0) ? 1.0 : -1.0) / (fabs(tau) + sqrt(1.0 + tau*tau));
                    c = 1.0 / sqrt(1.0 + tt*tt);
                    s = tt*c;
                }
                cr[t] = c; sr[t] = s; pa[t] = p; qa[t] = q;
            }
            __syncthreads();
            // column rotations on S_ and Q_
            #pragma unroll
            for (int it = 0; it < 8; ++it) {
                const int T = t + it*256;
                const int r = T >> 5, j = T & 31;
                const int p = pa[j], q = qa[j];
                const double c = cr[j], s = sr[j];
                double sp = S_[r][p], sq = S_[r][q];
                S_[r][p] = c*sp - s*sq;  S_[r][q] = s*sp + c*sq;
                double qp = Q_[r][p], qq2 = Q_[r][q];
                Q_[r][p] = c*qp - s*qq2; Q_[r][q] = s*qp + c*qq2;
            }
            __syncthreads();
            // row rotations on S_
            #pragma unroll
            for (int it = 0; it < 8; ++it) {
                const int T = t + it*256;
                const int cc = T >> 5, j = T & 31;
                const int p = pa[j], q = qa[j];
                const double c = cr[j], s = sr[j];
                double sp = S_[p][cc], sq = S_[q][cc];
                S_[p][cc] = c*sp - s*sq;  S_[q][cc] = s*sp + c*sq;
            }
            __syncthreads();
        }
    }
    // eigenvalues + cutoff
    if (t < 64) lam[t] = S_[t][t];
    __syncthreads();
    if (t < 64) {
        double v = lam[t];
        #pragma unroll
        for (int off = 32; off; off >>= 1) v = fmax(v, __shfl_xor(v, off));
        if (t == 0) lmax_s = v;
    }
    __syncthreads();
    const double rtol = 7.62939453125e-5;            // 10*64*eps_f32 (jax f32 default)
    const double lcut = lmax_s * (rtol*rtol);        // on lambda = sigma^2
    // M -> S_ : M[i][c] = w_i * sum_k Q_[k][i] * A_[c][k]
    {
        double mc[4][4] = {};
        for (int k = 0; k < 64; ++k) {
            double a[4], b[4];
            #pragma unroll
            for (int r = 0; r < 4; ++r) a[r] = Q_[k][i0+r];
            #pragma unroll
            for (int c = 0; c < 4; ++c) b[c] = A_[j0+c][k];
            #pragma unroll
            for (int r = 0; r < 4; ++r)
                #pragma unroll
                for (int c = 0; c < 4; ++c) mc[r][c] += a[r]*b[c];
        }
        #pragma unroll
        for (int r = 0; r < 4; ++r) {
            const double li = lam[i0+r];
            const double wi = (li > lcut) ? (1.0/li) : 0.0;
            #pragma unroll
            for (int c = 0; c < 4; ++c)
                S_[i0+r][j0+c] = mc[r][c]*wi;
        }
    }
    __syncthreads();
    // T -> A_ : T[i][d] = sum_c M[i][c] * k3s[c][d]
    {
        double tc[4][4] = {};
        for (int k = 0; k < 64; ++k) {
            double a[4], b[4];
            #pragma unroll
            for (int r = 0; r < 4; ++r) a[r] = S_[i0+r][k];
            #pragma unroll
            for (int c = 0; c < 4; ++c) b[c] = k3s[k][j0+c];
            #pragma unroll
            for (int r = 0; r < 4; ++r)
                #pragma unroll
                for (int c = 0; c < 4; ++c) tc[r][c] += a[r]*b[c];
        }
        __syncthreads();
        #pragma unroll
        for (int r = 0; r < 4; ++r)
            #pragma unroll
            for (int c = 0; c < 4; ++c)
                A_[i0+r][j0+c] = tc[r][c];
    }
    __syncthreads();
    // tmp2[m][d] = sum_i Q_[m][i] * T[i][d]
    {
        double oc[4][4] = {};
        for (int k = 0; k < 64; ++k) {
            double a[4], b[4];
            #pragma unroll
            for (int r = 0; r < 4; ++r) a[r] = Q_[i0+r][k];
            #pragma unroll
            for (int c = 0; c < 4; ++c) b[c] = A_[k][j0+c];
            #pragma unroll
            for (int r = 0; r < 4; ++r)
                #pragma unroll
                for (int c = 0; c < 4; ++c) oc[r][c] += a[r]*b[c];
        }
        #pragma unroll
        for (int r = 0; r < 4; ++r)
            #pragma unroll
            for (int c = 0; c < 4; ++c)
                t2[((long)z*64 + (i0+r))*64 + (j0+c)] = (float)oc[r][c];   // [z][m][d]
    }
}

// ======= host =======
extern "C" void kernel_launch(void* const* d_in, const int* in_sizes, int n_in,
                              void* d_out, int out_size, void* d_ws, size_t ws_size,
                              hipStream_t stream)
{
    const float* x      = (const float*)d_in[0];
    const float* w_qkv  = (const float*)d_in[1];
    const float* b_qkv  = (const float*)d_in[2];
    const float* w_proj = (const float*)d_in[3];
    const float* b_proj = (const float*)d_in[4];
    float* out = (float*)d_out;
    (void)in_sizes; (void)n_in; (void)out_size; (void)ws_size;

    char* ws = (char*)d_ws;
    size_t off = 0;
    auto alloc = [&](size_t bytes) -> void* {
        void* p = ws + off; off += (bytes + 255) & ~(size_t)255; return p;
    };
    float*  qbuf = (float*) alloc(16384ull*768*4);   // q; later reused as O
    float*  kbuf = (float*) alloc(16384ull*768*4);   // k; later reused as v
    float*  P1   = (float*) alloc(48ull*4096*64*4);
    double* QL   = (double*)alloc(48ull*64*64*8);
    double* KL   = (double*)alloc(48ull*64*64*8);
    float*  qlf  = (float*) alloc(48ull*64*64*4);
    float*  klf  = (float*) alloc(48ull*64*64*4);
    double* k3v  = (double*)alloc(48ull*64*64*8);
    float*  t2   = (float*) alloc(48ull*64*64*4);

    float* Lbuf = out;         // logits scratch in d_out
    float* vbuf = kbuf;        // v overlays k after L3
    float* Obuf = qbuf;        // O overlays q (q dead after L1)

    const float scale = 0.125f;

    // 1) landmarks at rows 65*m (f64 + f32 copies)
    landmark_kernel<<<48, 256, 0, stream>>>(x, w_qkv, b_qkv, QL, KL, qlf, klf);
    // 2) q = x @ Wq + bq
    gemm32<true,true><<<dim3(12,256,1), 256, 0, stream>>>(
        x, 768, 1, 0, 0,
        w_qkv, WLD, 1, 0, 0,
        qbuf, 768, 1, 0, 0, 768, b_qkv);
    // 3) k = x @ Wk + bk
    gemm32<true,true><<<dim3(12,256,1), 256, 0, stream>>>(
        x, 768, 1, 0, 0,
        w_qkv + 768, WLD, 1, 0, 0,
        kbuf, 768, 1, 0, 0, 768, b_qkv + 768);
    // 4) L1 = q @ k_l^T  -> d_out [b][n][h*64+m]
    gemm32<false,false><<<dim3(1,64,48), 256, 0, stream>>>(
        qbuf, 768, 12, (long)4096*768, 64,
        klf,  64,  1,  4096, 0,
        Lbuf, 768, 12, (long)4096*768, 64, 64, nullptr);
    // 5) P1 = softmax(L1) -> [z][n][m]
    softmax64_kernel<<<48*4096/4, 256, 0, stream>>>(Lbuf, P1, scale);
    // 6) L3 = q_l @ k^T -> d_out [b][h*64+m][n]
    gemm32<false,false><<<dim3(64,1,48), 256, 0, stream>>>(
        qlf,  64,  1,  4096, 0,
        kbuf, 768, 12, (long)4096*768, 64,
        Lbuf, 4096, 12, (long)768*4096, (long)64*4096, 64, nullptr);
    // 7) v = x @ Wv + bv   (k dead -> overlay)
    gemm32<true,true><<<dim3(12,256,1), 256, 0, stream>>>(
        x, 768, 1, 0, 0,
        w_qkv + 1536, WLD, 1, 0, 0,
        vbuf, 768, 1, 0, 0, 768, b_qkv + 1536);
    // 8) P3 = softmax(L3) in place
    softmax4096_kernel<<<4*768, 256, 0, stream>>>(Lbuf, scale);
    // 9) k3v = P3 @ v  (f64 accumulate) -> [z][m][d] f64
    k3v64_kernel<<<48, 256, 0, stream>>>(Lbuf, vbuf, k3v);
    // 10) truncated pinv (rcond = 10*64*eps_f32) + tmp2 = pinv @ k3v
    pinv_tmp2_kernel<<<48, 256, 0, stream>>>(QL, KL, k3v, t2);
    // 11) O = P1 @ tmp2 -> head-concat [b][n][h*64+d]
    gemm32<true,false><<<dim3(1,64,48), 256, 0, stream>>>(
        P1, 64, 1, (long)4096*64, 0,
        t2, 64, 1, 4096, 0,
        Obuf, 768, 12, (long)4096*768, 64, 64, nullptr);
    // 12) out = O @ Wp + bp
    gemm32<true,true><<<dim3(12,256,1), 256, 0, stream>>>(
        Obuf, 768, 1, 0, 0,
        w_proj, 768, 1, 0, 0,
        out, 768, 1, 0, 0, 768, b_proj);
}